// Round 10
// baseline (250.087 us; speedup 1.0000x reference)
//
#include <hip/hip_runtime.h>
#include <hip/hip_bf16.h>
#include <stdint.h>

typedef unsigned short u16;
typedef unsigned int u32;
typedef short short8 __attribute__((ext_vector_type(8)));
typedef float f32x4 __attribute__((ext_vector_type(4)));
typedef u32 u32x4 __attribute__((ext_vector_type(4)));
typedef u32 u32x2 __attribute__((ext_vector_type(2)));

#define DEV static __device__ __forceinline__

constexpr int Bsz = 4, Lseq = 2048, Dm = 1024, Hn = 16, Dk = 64;
constexpr float LOG2E = 1.44269504088896340736f;
constexpr float QSCALE = 0.125f * LOG2E;  // folded into Q projection

DEV u16 f2bf(float x) {
    u32 u = __builtin_bit_cast(u32, x);
    return (u16)((u + 0x7fffu + ((u >> 16) & 1u)) >> 16);
}

// pack 2 fp32 -> 2 bf16 in a u32 via HW v_cvt_pk_bf16_f32 path
DEV u32 pk2(float a, float b) {
    __hip_bfloat162 h = __float22bfloat162_rn(float2{a, b});
    u32 r;
    __builtin_memcpy(&r, &h, 4);
    return r;
}

// load 8 consecutive fp32, RNE to bf16, pack as u32x4
DEV u32x4 ld8_cvt(const float* p) {
    f32x4 lo = *(const f32x4*)p;
    f32x4 hi = *(const f32x4*)(p + 4);
    u32x4 r;
    r[0] = pk2(lo[0], lo[1]);
    r[1] = pk2(lo[2], lo[3]);
    r[2] = pk2(hi[0], hi[1]);
    r[3] = pk2(hi[2], hi[3]);
    return r;
}

// async global->LDS, 16B per lane; lds dest = wave-uniform base + lane*16
DEV void glds16(const void* g, void* l) {
    __builtin_amdgcn_global_load_lds(
        (const __attribute__((address_space(1))) void*)g,
        (__attribute__((address_space(3))) void*)l, 16, 0, 0);
}

// ---------------------------------------------------------------------------
// fp32 -> bf16 conversion, 8 elems/thread (proven R5)
// ---------------------------------------------------------------------------
__global__ __launch_bounds__(256) void cvt_f2b(
    const float* __restrict__ s, u16* __restrict__ d, int n8)
{
    int i = blockIdx.x * 256 + threadIdx.x;
    if (i >= n8) return;
    ((u32x4*)d)[i] = ld8_cvt(s + (long)i * 8);
}

// ---------------------------------------------------------------------------
// All-bf16 GEMM (R5-proven): C = (A[M,1024] @ W[N,1024]^T + bias) * scale
// global_load_lds w=16 both operands, 128x128 tile, BK=32, 4 waves (2x2).
// fp32 row-major [M,N] out (final projection).
// ---------------------------------------------------------------------------
__global__ __launch_bounds__(256) void gemm_glds(
    const u16* __restrict__ A, const u16* __restrict__ Bw,
    const float* __restrict__ bias, float* __restrict__ Cout, float scale)
{
    __shared__ u16 At[2][128 * 32];
    __shared__ u16 Bt[2][128 * 32];

    const int tid = threadIdx.x;
    const int lane = tid & 63, wid = tid >> 6;
    const int wr = wid >> 1, wc = wid & 1;
    const int mbase = blockIdx.x * 128, nbase = blockIdx.y * 128;

    f32x4 acc[4][4];
#pragma unroll
    for (int i = 0; i < 4; i++)
#pragma unroll
        for (int j = 0; j < 4; j++) acc[i][j] = (f32x4)0.f;

    const int srow = lane >> 2;
    const int sseg = (lane & 3) * 8;

    auto stage = [&](int kt, int buf) {
#pragma unroll
        for (int c = 0; c < 2; c++) {
            const int sec = wid * 2 + c;
            const long ko = (long)kt * 32 + sseg;
            glds16(A + (long)(mbase + sec * 16 + srow) * Dm + ko, &At[buf][sec * 512]);
            glds16(Bw + (long)(nbase + sec * 16 + srow) * Dm + ko, &Bt[buf][sec * 512]);
        }
    };

    stage(0, 0);
    __syncthreads();

    for (int kt = 0; kt < 32; kt++) {
        const int cur = kt & 1;
        if (kt + 1 < 32) stage(kt + 1, cur ^ 1);
        short8 af[4], bfr[4];
#pragma unroll
        for (int mf = 0; mf < 4; mf++)
            af[mf] = *(const short8*)&At[cur][(wr * 64 + mf * 16 + (lane & 15)) * 32 + (lane >> 4) * 8];
#pragma unroll
        for (int nf = 0; nf < 4; nf++)
            bfr[nf] = *(const short8*)&Bt[cur][(wc * 64 + nf * 16 + (lane & 15)) * 32 + (lane >> 4) * 8];
        __builtin_amdgcn_s_setprio(1);
#pragma unroll
        for (int mf = 0; mf < 4; mf++)
#pragma unroll
            for (int nf = 0; nf < 4; nf++)
                acc[mf][nf] = __builtin_amdgcn_mfma_f32_16x16x32_bf16(af[mf], bfr[nf], acc[mf][nf], 0, 0, 0);
        __builtin_amdgcn_s_setprio(0);
        __syncthreads();
    }

#pragma unroll
    for (int nf = 0; nf < 4; nf++) {
        const int n = nbase + wc * 64 + nf * 16 + (lane & 15);
        const float bv = bias[n];
#pragma unroll
        for (int mf = 0; mf < 4; mf++) {
            const int m0 = mbase + wr * 64 + mf * 16 + (lane >> 4) * 4;
#pragma unroll
            for (int r = 0; r < 4; r++) {
                const int m = m0 + r;
                Cout[(long)m * Dm + n] = (acc[mf][nf][r] + bv) * scale;
            }
        }
    }
}

// ---------------------------------------------------------------------------
// Hybrid GEMM (R7-proven): A fp32 reg-staged with in-flight cvt,
// B bf16 via global_load_lds w=16. One dispatch per projection (separate
// dispatches keep one X working set in L2 at a time — fused variant thrashed).
// Out: bf16 headed [B,H,L,DK].
// ---------------------------------------------------------------------------
__global__ __launch_bounds__(256) void gemm_hyb(
    const float* __restrict__ X, const u16* __restrict__ Bw,
    const float* __restrict__ bias, u16* __restrict__ Cout, float scale)
{
    __shared__ u16 At[2][128 * 32];
    __shared__ u16 Bt[2][128 * 32];

    const int tid = threadIdx.x;
    const int lane = tid & 63, wid = tid >> 6;
    const int wr = wid >> 1, wc = wid & 1;
    const int mbase = blockIdx.x * 128, nbase = blockIdx.y * 128;

    f32x4 acc[4][4];
#pragma unroll
    for (int i = 0; i < 4; i++)
#pragma unroll
        for (int j = 0; j < 4; j++) acc[i][j] = (f32x4)0.f;

    // B staging (glds, R5/R7-proven)
    const int srow = lane >> 2;
    const int sseg = (lane & 3) * 8;
    auto stageB = [&](int kt, int buf) {
#pragma unroll
        for (int c = 0; c < 2; c++) {
            const int sec = wid * 2 + c;
            glds16(Bw + (long)(nbase + sec * 16 + srow) * Dm + (long)kt * 32 + sseg,
                   &Bt[buf][sec * 512]);
        }
    };

    // A staging (reg + in-flight cvt, R4/R7-proven)
    u32x4 va[2];
    auto loadA = [&](int kt) {
#pragma unroll
        for (int i = 0; i < 2; i++) {
            int idx = i * 256 + tid;
            int row = idx >> 2, seg = idx & 3;
            va[i] = ld8_cvt(X + (long)(mbase + row) * Dm + (long)kt * 32 + seg * 8);
        }
    };
    auto writeA = [&](int buf) {
#pragma unroll
        for (int i = 0; i < 2; i++) {
            int idx = i * 256 + tid;
            *(u32x4*)&At[buf][idx * 8] = va[i];
        }
    };

    stageB(0, 0);
    loadA(0);
    writeA(0);
    __syncthreads();

    for (int kt = 0; kt < 32; kt++) {
        const int cur = kt & 1;
        const bool more = (kt + 1 < 32);
        if (more) {
            stageB(kt + 1, cur ^ 1);
            loadA(kt + 1);
        }
        short8 af[4], bfr[4];
#pragma unroll
        for (int mf = 0; mf < 4; mf++)
            af[mf] = *(const short8*)&At[cur][(wr * 64 + mf * 16 + (lane & 15)) * 32 + (lane >> 4) * 8];
#pragma unroll
        for (int nf = 0; nf < 4; nf++)
            bfr[nf] = *(const short8*)&Bt[cur][(wc * 64 + nf * 16 + (lane & 15)) * 32 + (lane >> 4) * 8];
        __builtin_amdgcn_s_setprio(1);
#pragma unroll
        for (int mf = 0; mf < 4; mf++)
#pragma unroll
            for (int nf = 0; nf < 4; nf++)
                acc[mf][nf] = __builtin_amdgcn_mfma_f32_16x16x32_bf16(af[mf], bfr[nf], acc[mf][nf], 0, 0, 0);
        __builtin_amdgcn_s_setprio(0);
        if (more) writeA(cur ^ 1);
        __syncthreads();
    }

#pragma unroll
    for (int nf = 0; nf < 4; nf++) {
        const int n = nbase + wc * 64 + nf * 16 + (lane & 15);
        const float bv = bias[n];
#pragma unroll
        for (int mf = 0; mf < 4; mf++) {
            const int m0 = mbase + wr * 64 + mf * 16 + (lane >> 4) * 4;
#pragma unroll
            for (int r = 0; r < 4; r++) {
                const int m = m0 + r;
                const float v = (acc[mf][nf][r] + bv) * scale;
                int b = m >> 11, l = m & 2047, h = n >> 6, dk = n & 63;
                long addr = ((long)(b * Hn + h) * Lseq + l) * Dk + dk;
                Cout[addr] = f2bf(v);
            }
        }
    }
}

// ---------------------------------------------------------------------------
// Flash attention (R9-proven). Causal, base-2 softmax (Q pre-scaled by
// 1/8*log2e). Grid: (B*H, L/128), qt reversed. Block 256 = 4 waves,
// wave w owns q rows [qt*128+w*32, +32). Double-buffered K/V, 1 barrier/iter.
// K: glds w=16 with pre-swizzled source; read col ^ ((kv&7)<<3).
// V: reg transpose-staged Vt[d][kv ^ (((d&7)^(d>>3))<<3)].
// P: per-wave [32q][32kv] (8 KB) time-shared across the two kf2 PV phases —
//    LDS 40 KB. Swizzle: granule ^ (q&7) on 4-col granules.
// Defer-max (THR=8) + lane-partial l. setprio around MFMA clusters.
// ---------------------------------------------------------------------------
__global__ __launch_bounds__(256) void attn_fwd(
    const u16* __restrict__ Qb, const u16* __restrict__ Kb,
    const u16* __restrict__ Vb, u16* __restrict__ Ctx)
{
    __shared__ u16 Kt[2][64 * 64];
    __shared__ u16 Vt[2][64 * 64];
    __shared__ u16 Pq[4][32 * 32];

    const int tid = threadIdx.x, lane = tid & 63, w = tid >> 6;
    const int qt = gridDim.y - 1 - blockIdx.y;  // heavy-first
    const int bh = blockIdx.x;
    const long base = (long)bh * Lseq * Dk;
    const int qw = qt * 128 + w * 32;

    const int krow_in_w = lane >> 3;
    const int kseg = lane & 7;
    const int skv = tid >> 3, sdb = (tid & 7) * 8;

    auto stage_k = [&](int kvbase, int buf) {
#pragma unroll
        for (int c = 0; c < 2; c++) {
            int kv = w * 16 + c * 8 + krow_in_w;
            int d0 = ((kseg ^ (kv & 7)) * 8);
            glds16(Kb + base + (long)(kvbase + kv) * Dk + d0,
                   &Kt[buf][(w * 16 + c * 8) * 64]);
        }
    };

    // Q fragments in registers (log2 domain)
    short8 qfr[2][2];
#pragma unroll
    for (int qf = 0; qf < 2; qf++)
#pragma unroll
        for (int ks = 0; ks < 2; ks++) {
            int q = qw + qf * 16 + (lane & 15);
            int d0 = ks * 32 + (lane >> 4) * 8;
            qfr[qf][ks] = *(const short8*)(Qb + base + (long)q * Dk + d0);
        }

    f32x4 accT[4][2];  // ctx^T: [dkf][qf]
#pragma unroll
    for (int i = 0; i < 4; i++)
#pragma unroll
        for (int j = 0; j < 2; j++) accT[i][j] = (f32x4)0.f;
    float m_run[2] = {-__builtin_inff(), -__builtin_inff()};
    float l_part[2] = {0.f, 0.f};

    u32x4 vr[2];
    stage_k(0, 0);
#pragma unroll
    for (int i = 0; i < 2; i++)
        vr[i] = *(const u32x4*)(Vb + base + (long)(i * 32 + skv) * Dk + sdb);
#pragma unroll
    for (int i = 0; i < 2; i++) {
        int kv = i * 32 + skv;
        const u16* pv = (const u16*)&vr[i];
#pragma unroll
        for (int j = 0; j < 8; j++) {
            int d = sdb + j;
            Vt[0][d * 64 + (kv ^ ((((d & 7) ^ (d >> 3)) & 7) << 3))] = pv[j];
        }
    }
    __syncthreads();

    const int nkv = qt * 2 + 2;
    const int myn = ((qw + 31) >> 6) + 1;  // tiles this wave computes

    for (int kvt = 0; kvt < nkv; kvt++) {
        const int cur = kvt & 1;
        const bool more = (kvt + 1 < nkv);
        const int kvbase = kvt * 64;

        if (more) {
            stage_k(kvbase + 64, cur ^ 1);
#pragma unroll
            for (int i = 0; i < 2; i++)
                vr[i] = *(const u32x4*)(Vb + base + (long)(kvbase + 64 + i * 32 + skv) * Dk + sdb);
        }

        if (kvt < myn) {
            // ---- S^T = K @ Q^T
            f32x4 st[4][2];
#pragma unroll
            for (int i = 0; i < 4; i++)
#pragma unroll
                for (int j = 0; j < 2; j++) st[i][j] = (f32x4)0.f;
            __builtin_amdgcn_s_setprio(1);
#pragma unroll
            for (int ks = 0; ks < 2; ks++) {
                short8 kf[4];
#pragma unroll
                for (int kvf = 0; kvf < 4; kvf++) {
                    int row = kvf * 16 + (lane & 15);
                    int d0 = ks * 32 + (lane >> 4) * 8;
                    kf[kvf] = *(const short8*)&Kt[cur][row * 64 + (d0 ^ ((row & 7) << 3))];
                }
#pragma unroll
                for (int kvf = 0; kvf < 4; kvf++)
#pragma unroll
                    for (int qf = 0; qf < 2; qf++)
                        st[kvf][qf] = __builtin_amdgcn_mfma_f32_16x16x32_bf16(kf[kvf], qfr[qf][ks], st[kvf][qf], 0, 0, 0);
            }
            __builtin_amdgcn_s_setprio(0);

            // ---- causal mask (diagonal tiles only)
            if ((kvbase + 63) > qw) {
#pragma unroll
                for (int qf = 0; qf < 2; qf++) {
                    const int q = qw + qf * 16 + (lane & 15);
#pragma unroll
                    for (int kvf = 0; kvf < 4; kvf++)
#pragma unroll
                        for (int r = 0; r < 4; r++) {
                            int kv = kvbase + kvf * 16 + (lane >> 4) * 4 + r;
                            if (kv > q) st[kvf][qf][r] = -1e30f;
                        }
                }
            }

            // ---- online softmax (base 2), defer-max, lane-partial l
#pragma unroll
            for (int qf = 0; qf < 2; qf++) {
                float tmax = st[0][qf][0];
#pragma unroll
                for (int kvf = 0; kvf < 4; kvf++)
#pragma unroll
                    for (int r = 0; r < 4; r++) tmax = fmaxf(tmax, st[kvf][qf][r]);
                tmax = fmaxf(tmax, __shfl_xor(tmax, 16, 64));
                tmax = fmaxf(tmax, __shfl_xor(tmax, 32, 64));
                const bool norescale = __all((int)(tmax <= m_run[qf] + 8.f));
                if (!norescale) {
                    const float mnew = fmaxf(m_run[qf], tmax);
                    const float sc = __builtin_exp2f(m_run[qf] - mnew);
                    m_run[qf] = mnew;
                    l_part[qf] *= sc;
#pragma unroll
                    for (int dkf = 0; dkf < 4; dkf++)
#pragma unroll
                        for (int r = 0; r < 4; r++) accT[dkf][qf][r] *= sc;
                }
                const float mq = m_run[qf];
                float ts = 0.f;
#pragma unroll
                for (int kvf = 0; kvf < 4; kvf++)
#pragma unroll
                    for (int r = 0; r < 4; r++) {
                        float p = __builtin_exp2f(st[kvf][qf][r] - mq);
                        st[kvf][qf][r] = p;
                        ts += p;
                    }
                l_part[qf] += ts;
            }

            // ---- PV: ctx^T += V^T @ P^T  (P staged per 32-kv half, 8KB)
#pragma unroll
            for (int kf2 = 0; kf2 < 2; kf2++) {
                // write this half of P (local kv 0..31)
#pragma unroll
                for (int qf = 0; qf < 2; qf++) {
                    const int qrow = qf * 16 + (lane & 15);
#pragma unroll
                    for (int k2 = 0; k2 < 2; k2++) {
                        const int kvf = kf2 * 2 + k2;
                        u32x2 pk;
                        pk[0] = pk2(st[kvf][qf][0], st[kvf][qf][1]);
                        pk[1] = pk2(st[kvf][qf][2], st[kvf][qf][3]);
                        const int kvi = (k2 * 16 + (lane >> 4) * 4) ^ ((lane & 7) << 2);
                        *(u32x2*)&Pq[w][qrow * 32 + kvi] = pk;
                    }
                }
                short8 vfr[4];
#pragma unroll
                for (int dkf = 0; dkf < 4; dkf++) {
                    int d = dkf * 16 + (lane & 15);
                    int kvi = (kf2 * 32 + (lane >> 4) * 8) ^ ((((d & 7) ^ (d >> 3)) & 7) << 3);
                    vfr[dkf] = *(const short8*)&Vt[cur][d * 64 + kvi];
                }
                short8 pfr[2];
#pragma unroll
                for (int qf = 0; qf < 2; qf++) {
                    const int qrow = qf * 16 + (lane & 15);
                    u32x2 lohi[2];
#pragma unroll
                    for (int h = 0; h < 2; h++) {
                        const int kvi = ((lane >> 4) * 8 + h * 4) ^ ((lane & 7) << 2);
                        lohi[h] = *(const u32x2*)&Pq[w][qrow * 32 + kvi];
                    }
                    __builtin_memcpy(&pfr[qf], lohi, 16);
                }
                __builtin_amdgcn_s_setprio(1);
#pragma unroll
                for (int dkf = 0; dkf < 4; dkf++)
#pragma unroll
                    for (int qf = 0; qf < 2; qf++)
                        accT[dkf][qf] = __builtin_amdgcn_mfma_f32_16x16x32_bf16(vfr[dkf], pfr[qf], accT[dkf][qf], 0, 0, 0);
                __builtin_amdgcn_s_setprio(0);
            }
        }

        // write staged V regs into the other buffer
        if (more) {
#pragma unroll
            for (int i = 0; i < 2; i++) {
                int kv = i * 32 + skv;
                const u16* pv = (const u16*)&vr[i];
#pragma unroll
                for (int j = 0; j < 8; j++) {
                    int d = sdb + j;
                    Vt[cur ^ 1][d * 64 + (kv ^ ((((d & 7) ^ (d >> 3)) & 7) << 3))] = pv[j];
                }
            }
        }
        __syncthreads();  // drains glds (vmcnt) for buf^1
    }

    // ---- epilogue: reduce l, divide, write bf16 [B,L,D]
    const int b = bh >> 4, h = bh & 15;
#pragma unroll
    for (int qf = 0; qf < 2; qf++) {
        float l = l_part[qf];
        l += __shfl_xor(l, 16, 64);
        l += __shfl_xor(l, 32, 64);
        const float inv = 1.f / l;
        const int q = qw + qf * 16 + (lane & 15);
#pragma unroll
        for (int dkf = 0; dkf < 4; dkf++) {
            const int dk0 = dkf * 16 + (lane >> 4) * 4;
            u32x2 o;
            o[0] = pk2(accT[dkf][qf][0] * inv, accT[dkf][qf][1] * inv);
            o[1] = pk2(accT[dkf][qf][2] * inv, accT[dkf][qf][3] * inv);
            long addr = ((long)b * Lseq + q) * Dm + h * Dk + dk0;
            *(u32x2*)(Ctx + addr) = o;
        }
    }
}

// ---------------------------------------------------------------------------
extern "C" void kernel_launch(void* const* d_in, const int* in_sizes, int n_in,
                              void* d_out, int out_size, void* d_ws, size_t ws_size,
                              hipStream_t stream)
{
    const float* query = (const float*)d_in[0];
    const float* key_  = (const float*)d_in[1];
    const float* value = (const float*)d_in[2];
    const float* Wq = (const float*)d_in[3];
    const float* bq = (const float*)d_in[4];
    const float* Wk = (const float*)d_in[5];
    const float* bk = (const float*)d_in[6];
    const float* Wv = (const float*)d_in[7];
    const float* bv = (const float*)d_in[8];
    const float* Wo = (const float*)d_in[9];
    const float* bo = (const float*)d_in[10];
    // d_in[11] = attn_mask (bool causal) — derived from indices instead.

    float* out = (float*)d_out;
    const size_t tens = (size_t)Bsz * Lseq * Dm;   // 8,388,608
    const size_t wTot = (size_t)Dm * Dm;           // 1,048,576
    // ws layout (4*tens*2B = 67.1 MB, proven available):
    u16* Qb = (u16*)d_ws;        // bf16 [B,H,L,DK] (Q pre-scaled)
    u16* Kb = Qb + tens;
    u16* Vb = Kb + tens;
    u16* Cx = Vb + tens;         // attn output [B,L,D]
    // weight bf16 buffers alias dead regions:
    u16* Wqb = Cx;               // Wq/Wk/Wv live in Cx slot until attn
    u16* Wkb = Wqb + wTot;
    u16* Wvb = Wkb + wTot;
    u16* Wob = Qb;               // converted AFTER attn (Qb dead by then)

    dim3 blk(256), g(64, 8);
    const int n8w = (int)(wTot / 8);
    const int gw = (n8w + 255) / 256;

    cvt_f2b<<<gw, blk, 0, stream>>>(Wq, Wqb, n8w);
    cvt_f2b<<<gw, blk, 0, stream>>>(Wk, Wkb, n8w);
    cvt_f2b<<<gw, blk, 0, stream>>>(Wv, Wvb, n8w);
    gemm_hyb<<<g, blk, 0, stream>>>(query, Wqb, bq, Qb, QSCALE);
    gemm_hyb<<<g, blk, 0, stream>>>(key_,  Wkb, bk, Kb, 1.0f);
    gemm_hyb<<<g, blk, 0, stream>>>(value, Wvb, bv, Vb, 1.0f);
    attn_fwd<<<dim3(Bsz * Hn, Lseq / 128), blk, 0, stream>>>(Qb, Kb, Vb, Cx);
    cvt_f2b<<<gw, blk, 0, stream>>>(Wo, Wob, n8w);
    gemm_glds<<<g, blk, 0, stream>>>(Cx, Wob, bo, out, 1.0f);
}

// Round 11
// 216.385 us; speedup vs baseline: 1.1558x; 1.1558x over previous
//
#include <hip/hip_runtime.h>
#include <hip/hip_bf16.h>
#include <stdint.h>

typedef unsigned short u16;
typedef unsigned int u32;
typedef short short8 __attribute__((ext_vector_type(8)));
typedef float f32x4 __attribute__((ext_vector_type(4)));
typedef u32 u32x4 __attribute__((ext_vector_type(4)));
typedef u32 u32x2 __attribute__((ext_vector_type(2)));

#define DEV static __device__ __forceinline__

constexpr int Bsz = 4, Lseq = 2048, Dm = 1024, Hn = 16, Dk = 64;
constexpr float LOG2E = 1.44269504088896340736f;
constexpr float QSCALE = 0.125f * LOG2E;  // folded into Q projection

DEV u16 f2bf(float x) {
    u32 u = __builtin_bit_cast(u32, x);
    return (u16)((u + 0x7fffu + ((u >> 16) & 1u)) >> 16);
}

// pack 2 fp32 -> 2 bf16 in a u32 via HW v_cvt_pk_bf16_f32 path
DEV u32 pk2(float a, float b) {
    __hip_bfloat162 h = __float22bfloat162_rn(float2{a, b});
    u32 r;
    __builtin_memcpy(&r, &h, 4);
    return r;
}

// load 8 consecutive fp32, RNE to bf16, pack as u32x4
DEV u32x4 ld8_cvt(const float* p) {
    f32x4 lo = *(const f32x4*)p;
    f32x4 hi = *(const f32x4*)(p + 4);
    u32x4 r;
    r[0] = pk2(lo[0], lo[1]);
    r[1] = pk2(lo[2], lo[3]);
    r[2] = pk2(hi[0], hi[1]);
    r[3] = pk2(hi[2], hi[3]);
    return r;
}

// async global->LDS, 16B per lane; lds dest = wave-uniform base + lane*16
DEV void glds16(const void* g, void* l) {
    __builtin_amdgcn_global_load_lds(
        (const __attribute__((address_space(1))) void*)g,
        (__attribute__((address_space(3))) void*)l, 16, 0, 0);
}

// ---------------------------------------------------------------------------
// fp32 -> bf16 conversion, 8 elems/thread (proven R5)
// ---------------------------------------------------------------------------
__global__ __launch_bounds__(256) void cvt_f2b(
    const float* __restrict__ s, u16* __restrict__ d, int n8)
{
    int i = blockIdx.x * 256 + threadIdx.x;
    if (i >= n8) return;
    ((u32x4*)d)[i] = ld8_cvt(s + (long)i * 8);
}

// ---------------------------------------------------------------------------
// All-bf16 GEMM (R5-proven): C = (A[M,1024] @ W[N,1024]^T + bias) * scale
// global_load_lds w=16 both operands, 128x128 tile, BK=32, 4 waves (2x2).
// fp32 row-major [M,N] out (final projection).
// ---------------------------------------------------------------------------
__global__ __launch_bounds__(256) void gemm_glds(
    const u16* __restrict__ A, const u16* __restrict__ Bw,
    const float* __restrict__ bias, float* __restrict__ Cout, float scale)
{
    __shared__ u16 At[2][128 * 32];
    __shared__ u16 Bt[2][128 * 32];

    const int tid = threadIdx.x;
    const int lane = tid & 63, wid = tid >> 6;
    const int wr = wid >> 1, wc = wid & 1;
    const int mbase = blockIdx.x * 128, nbase = blockIdx.y * 128;

    f32x4 acc[4][4];
#pragma unroll
    for (int i = 0; i < 4; i++)
#pragma unroll
        for (int j = 0; j < 4; j++) acc[i][j] = (f32x4)0.f;

    const int srow = lane >> 2;
    const int sseg = (lane & 3) * 8;

    auto stage = [&](int kt, int buf) {
#pragma unroll
        for (int c = 0; c < 2; c++) {
            const int sec = wid * 2 + c;
            const long ko = (long)kt * 32 + sseg;
            glds16(A + (long)(mbase + sec * 16 + srow) * Dm + ko, &At[buf][sec * 512]);
            glds16(Bw + (long)(nbase + sec * 16 + srow) * Dm + ko, &Bt[buf][sec * 512]);
        }
    };

    stage(0, 0);
    __syncthreads();

    for (int kt = 0; kt < 32; kt++) {
        const int cur = kt & 1;
        if (kt + 1 < 32) stage(kt + 1, cur ^ 1);
        short8 af[4], bfr[4];
#pragma unroll
        for (int mf = 0; mf < 4; mf++)
            af[mf] = *(const short8*)&At[cur][(wr * 64 + mf * 16 + (lane & 15)) * 32 + (lane >> 4) * 8];
#pragma unroll
        for (int nf = 0; nf < 4; nf++)
            bfr[nf] = *(const short8*)&Bt[cur][(wc * 64 + nf * 16 + (lane & 15)) * 32 + (lane >> 4) * 8];
        __builtin_amdgcn_s_setprio(1);
#pragma unroll
        for (int mf = 0; mf < 4; mf++)
#pragma unroll
            for (int nf = 0; nf < 4; nf++)
                acc[mf][nf] = __builtin_amdgcn_mfma_f32_16x16x32_bf16(af[mf], bfr[nf], acc[mf][nf], 0, 0, 0);
        __builtin_amdgcn_s_setprio(0);
        __syncthreads();
    }

#pragma unroll
    for (int nf = 0; nf < 4; nf++) {
        const int n = nbase + wc * 64 + nf * 16 + (lane & 15);
        const float bv = bias[n];
#pragma unroll
        for (int mf = 0; mf < 4; mf++) {
            const int m0 = mbase + wr * 64 + mf * 16 + (lane >> 4) * 4;
#pragma unroll
            for (int r = 0; r < 4; r++) {
                const int m = m0 + r;
                Cout[(long)m * Dm + n] = (acc[mf][nf][r] + bv) * scale;
            }
        }
    }
}

// ---------------------------------------------------------------------------
// Fused QKV GEMM (R9-proven WIN): one 1536-block dispatch computes all three
// projections (fills CU slots that a 512-block dispatch leaves empty).
// t = blockIdx.y>>3 selects {X, W slab, bias, scale, output} (block-uniform).
// A fp32 reg-staged with in-flight cvt; B bf16 via glds w=16.
// Out: bf16 headed [B,H,L,DK].
// ---------------------------------------------------------------------------
__global__ __launch_bounds__(256) void gemm_qkv(
    const float* __restrict__ Xq, const float* __restrict__ Xk,
    const float* __restrict__ Xv, const u16* __restrict__ Wb3,
    const float* __restrict__ bq, const float* __restrict__ bk,
    const float* __restrict__ bv, u16* __restrict__ Out3)
{
    __shared__ u16 At[2][128 * 32];
    __shared__ u16 Bt[2][128 * 32];

    const int tid = threadIdx.x;
    const int lane = tid & 63, wid = tid >> 6;
    const int wr = wid >> 1, wc = wid & 1;
    const int mbase = blockIdx.x * 128;
    const int t = blockIdx.y >> 3;              // 0:Q 1:K 2:V (block-uniform)
    const int nbase = (blockIdx.y & 7) * 128;
    const float* X = t == 0 ? Xq : (t == 1 ? Xk : Xv);
    const u16* Bw = Wb3 + (size_t)t * Dm * Dm;
    const float* bias = t == 0 ? bq : (t == 1 ? bk : bv);
    const float scale = t == 0 ? QSCALE : 1.0f;
    u16* Cout = Out3 + (size_t)t * ((size_t)Bsz * Lseq * Dm);

    f32x4 acc[4][4];
#pragma unroll
    for (int i = 0; i < 4; i++)
#pragma unroll
        for (int j = 0; j < 4; j++) acc[i][j] = (f32x4)0.f;

    // B staging (glds, R5/R7-proven)
    const int srow = lane >> 2;
    const int sseg = (lane & 3) * 8;
    auto stageB = [&](int kt, int buf) {
#pragma unroll
        for (int c = 0; c < 2; c++) {
            const int sec = wid * 2 + c;
            glds16(Bw + (long)(nbase + sec * 16 + srow) * Dm + (long)kt * 32 + sseg,
                   &Bt[buf][sec * 512]);
        }
    };

    // A staging (reg + in-flight cvt, R4/R7-proven)
    u32x4 va[2];
    auto loadA = [&](int kt) {
#pragma unroll
        for (int i = 0; i < 2; i++) {
            int idx = i * 256 + tid;
            int row = idx >> 2, seg = idx & 3;
            va[i] = ld8_cvt(X + (long)(mbase + row) * Dm + (long)kt * 32 + seg * 8);
        }
    };
    auto writeA = [&](int buf) {
#pragma unroll
        for (int i = 0; i < 2; i++) {
            int idx = i * 256 + tid;
            *(u32x4*)&At[buf][idx * 8] = va[i];
        }
    };

    stageB(0, 0);
    loadA(0);
    writeA(0);
    __syncthreads();

    for (int kt = 0; kt < 32; kt++) {
        const int cur = kt & 1;
        const bool more = (kt + 1 < 32);
        if (more) {
            stageB(kt + 1, cur ^ 1);
            loadA(kt + 1);
        }
        short8 af[4], bfr[4];
#pragma unroll
        for (int mf = 0; mf < 4; mf++)
            af[mf] = *(const short8*)&At[cur][(wr * 64 + mf * 16 + (lane & 15)) * 32 + (lane >> 4) * 8];
#pragma unroll
        for (int nf = 0; nf < 4; nf++)
            bfr[nf] = *(const short8*)&Bt[cur][(wc * 64 + nf * 16 + (lane & 15)) * 32 + (lane >> 4) * 8];
        __builtin_amdgcn_s_setprio(1);
#pragma unroll
        for (int mf = 0; mf < 4; mf++)
#pragma unroll
            for (int nf = 0; nf < 4; nf++)
                acc[mf][nf] = __builtin_amdgcn_mfma_f32_16x16x32_bf16(af[mf], bfr[nf], acc[mf][nf], 0, 0, 0);
        __builtin_amdgcn_s_setprio(0);
        if (more) writeA(cur ^ 1);
        __syncthreads();
    }

#pragma unroll
    for (int nf = 0; nf < 4; nf++) {
        const int n = nbase + wc * 64 + nf * 16 + (lane & 15);
        const float bv = bias[n];
#pragma unroll
        for (int mf = 0; mf < 4; mf++) {
            const int m0 = mbase + wr * 64 + mf * 16 + (lane >> 4) * 4;
#pragma unroll
            for (int r = 0; r < 4; r++) {
                const int m = m0 + r;
                const float v = (acc[mf][nf][r] + bv) * scale;
                int b = m >> 11, l = m & 2047, h = n >> 6, dk = n & 63;
                long addr = ((long)(b * Hn + h) * Lseq + l) * Dk + dk;
                Cout[addr] = f2bf(v);
            }
        }
    }
}

// ---------------------------------------------------------------------------
// Flash attention (R7-proven, 48KB full-P version — the 40KB time-shared P
// regressed: +50% bank conflicts, no occupancy gain). Causal, base-2 softmax
// (Q pre-scaled by 1/8*log2e). Grid: (B*H, L/128), qt reversed. 4 waves,
// wave w owns q rows [qt*128+w*32, +32). Double-buffered K/V, 1 barrier/iter.
// K: glds w=16 with pre-swizzled source; read col ^ ((kv&7)<<3).
// V: reg transpose-staged Vt[d][kv ^ (((d&7)^(d>>3))<<3)].
// P per-wave [32q][64kv], col ^ ((q&7)<<3). Defer-max (THR=8) +
// lane-partial l. setprio around MFMA clusters.
// ---------------------------------------------------------------------------
__global__ __launch_bounds__(256) void attn_fwd(
    const u16* __restrict__ Qb, const u16* __restrict__ Kb,
    const u16* __restrict__ Vb, u16* __restrict__ Ctx)
{
    __shared__ u16 Kt[2][64 * 64];
    __shared__ u16 Vt[2][64 * 64];
    __shared__ u16 Pq[4][32 * 64];

    const int tid = threadIdx.x, lane = tid & 63, w = tid >> 6;
    const int qt = gridDim.y - 1 - blockIdx.y;  // heavy-first
    const int bh = blockIdx.x;
    const long base = (long)bh * Lseq * Dk;
    const int qw = qt * 128 + w * 32;

    const int krow_in_w = lane >> 3;
    const int kseg = lane & 7;
    const int skv = tid >> 3, sdb = (tid & 7) * 8;

    auto stage_k = [&](int kvbase, int buf) {
#pragma unroll
        for (int c = 0; c < 2; c++) {
            int kv = w * 16 + c * 8 + krow_in_w;
            int d0 = ((kseg ^ (kv & 7)) * 8);
            glds16(Kb + base + (long)(kvbase + kv) * Dk + d0,
                   &Kt[buf][(w * 16 + c * 8) * 64]);
        }
    };

    // Q fragments in registers (log2 domain)
    short8 qfr[2][2];
#pragma unroll
    for (int qf = 0; qf < 2; qf++)
#pragma unroll
        for (int ks = 0; ks < 2; ks++) {
            int q = qw + qf * 16 + (lane & 15);
            int d0 = ks * 32 + (lane >> 4) * 8;
            qfr[qf][ks] = *(const short8*)(Qb + base + (long)q * Dk + d0);
        }

    f32x4 accT[4][2];  // ctx^T: [dkf][qf]
#pragma unroll
    for (int i = 0; i < 4; i++)
#pragma unroll
        for (int j = 0; j < 2; j++) accT[i][j] = (f32x4)0.f;
    float m_run[2] = {-__builtin_inff(), -__builtin_inff()};
    float l_part[2] = {0.f, 0.f};

    u32x4 vr[2];
    stage_k(0, 0);
#pragma unroll
    for (int i = 0; i < 2; i++)
        vr[i] = *(const u32x4*)(Vb + base + (long)(i * 32 + skv) * Dk + sdb);
#pragma unroll
    for (int i = 0; i < 2; i++) {
        int kv = i * 32 + skv;
        const u16* pv = (const u16*)&vr[i];
#pragma unroll
        for (int j = 0; j < 8; j++) {
            int d = sdb + j;
            Vt[0][d * 64 + (kv ^ ((((d & 7) ^ (d >> 3)) & 7) << 3))] = pv[j];
        }
    }
    __syncthreads();

    const int nkv = qt * 2 + 2;
    const int myn = ((qw + 31) >> 6) + 1;  // tiles this wave computes

    for (int kvt = 0; kvt < nkv; kvt++) {
        const int cur = kvt & 1;
        const bool more = (kvt + 1 < nkv);
        const int kvbase = kvt * 64;

        if (more) {
            stage_k(kvbase + 64, cur ^ 1);
#pragma unroll
            for (int i = 0; i < 2; i++)
                vr[i] = *(const u32x4*)(Vb + base + (long)(kvbase + 64 + i * 32 + skv) * Dk + sdb);
        }

        if (kvt < myn) {
            // ---- S^T = K @ Q^T
            f32x4 st[4][2];
#pragma unroll
            for (int i = 0; i < 4; i++)
#pragma unroll
                for (int j = 0; j < 2; j++) st[i][j] = (f32x4)0.f;
            __builtin_amdgcn_s_setprio(1);
#pragma unroll
            for (int ks = 0; ks < 2; ks++) {
                short8 kf[4];
#pragma unroll
                for (int kvf = 0; kvf < 4; kvf++) {
                    int row = kvf * 16 + (lane & 15);
                    int d0 = ks * 32 + (lane >> 4) * 8;
                    kf[kvf] = *(const short8*)&Kt[cur][row * 64 + (d0 ^ ((row & 7) << 3))];
                }
#pragma unroll
                for (int kvf = 0; kvf < 4; kvf++)
#pragma unroll
                    for (int qf = 0; qf < 2; qf++)
                        st[kvf][qf] = __builtin_amdgcn_mfma_f32_16x16x32_bf16(kf[kvf], qfr[qf][ks], st[kvf][qf], 0, 0, 0);
            }
            __builtin_amdgcn_s_setprio(0);

            // ---- causal mask (diagonal tiles only)
            if ((kvbase + 63) > qw) {
#pragma unroll
                for (int qf = 0; qf < 2; qf++) {
                    const int q = qw + qf * 16 + (lane & 15);
#pragma unroll
                    for (int kvf = 0; kvf < 4; kvf++)
#pragma unroll
                        for (int r = 0; r < 4; r++) {
                            int kv = kvbase + kvf * 16 + (lane >> 4) * 4 + r;
                            if (kv > q) st[kvf][qf][r] = -1e30f;
                        }
                }
            }

            // ---- online softmax (base 2), defer-max, lane-partial l
#pragma unroll
            for (int qf = 0; qf < 2; qf++) {
                float tmax = st[0][qf][0];
#pragma unroll
                for (int kvf = 0; kvf < 4; kvf++)
#pragma unroll
                    for (int r = 0; r < 4; r++) tmax = fmaxf(tmax, st[kvf][qf][r]);
                tmax = fmaxf(tmax, __shfl_xor(tmax, 16, 64));
                tmax = fmaxf(tmax, __shfl_xor(tmax, 32, 64));
                const bool norescale = __all((int)(tmax <= m_run[qf] + 8.f));
                if (!norescale) {
                    const float mnew = fmaxf(m_run[qf], tmax);
                    const float sc = __builtin_exp2f(m_run[qf] - mnew);
                    m_run[qf] = mnew;
                    l_part[qf] *= sc;
#pragma unroll
                    for (int dkf = 0; dkf < 4; dkf++)
#pragma unroll
                        for (int r = 0; r < 4; r++) accT[dkf][qf][r] *= sc;
                }
                const float mq = m_run[qf];
                float ts = 0.f;
#pragma unroll
                for (int kvf = 0; kvf < 4; kvf++)
#pragma unroll
                    for (int r = 0; r < 4; r++) {
                        float p = __builtin_exp2f(st[kvf][qf][r] - mq);
                        st[kvf][qf][r] = p;
                        ts += p;
                    }
                l_part[qf] += ts;
                const int qrow = qf * 16 + (lane & 15);
#pragma unroll
                for (int kvf = 0; kvf < 4; kvf++) {
                    u32x2 pk;
                    pk[0] = pk2(st[kvf][qf][0], st[kvf][qf][1]);
                    pk[1] = pk2(st[kvf][qf][2], st[kvf][qf][3]);
                    int kvi = (kvf * 16 + (lane >> 4) * 4) ^ ((lane & 7) << 3);
                    *(u32x2*)&Pq[w][qrow * 64 + kvi] = pk;
                }
            }

            // ---- PV: ctx^T += V^T @ P^T
#pragma unroll
            for (int kf2 = 0; kf2 < 2; kf2++) {
                short8 vfr[4];
#pragma unroll
                for (int dkf = 0; dkf < 4; dkf++) {
                    int d = dkf * 16 + (lane & 15);
                    int kvi = (kf2 * 32 + (lane >> 4) * 8) ^ ((((d & 7) ^ (d >> 3)) & 7) << 3);
                    vfr[dkf] = *(const short8*)&Vt[cur][d * 64 + kvi];
                }
                short8 pfr[2];
#pragma unroll
                for (int qf = 0; qf < 2; qf++) {
                    int qrow = qf * 16 + (lane & 15);
                    int kvi = (kf2 * 32 + (lane >> 4) * 8) ^ ((lane & 7) << 3);
                    pfr[qf] = *(const short8*)&Pq[w][qrow * 64 + kvi];
                }
                __builtin_amdgcn_s_setprio(1);
#pragma unroll
                for (int dkf = 0; dkf < 4; dkf++)
#pragma unroll
                    for (int qf = 0; qf < 2; qf++)
                        accT[dkf][qf] = __builtin_amdgcn_mfma_f32_16x16x32_bf16(vfr[dkf], pfr[qf], accT[dkf][qf], 0, 0, 0);
                __builtin_amdgcn_s_setprio(0);
            }
        }

        // write staged V regs into the other buffer
        if (more) {
#pragma unroll
            for (int i = 0; i < 2; i++) {
                int kv = i * 32 + skv;
                const u16* pv = (const u16*)&vr[i];
#pragma unroll
                for (int j = 0; j < 8; j++) {
                    int d = sdb + j;
                    Vt[cur ^ 1][d * 64 + (kv ^ ((((d & 7) ^ (d >> 3)) & 7) << 3))] = pv[j];
                }
            }
        }
        __syncthreads();  // drains glds (vmcnt) for buf^1
    }

    // ---- epilogue: reduce l, divide, write bf16 [B,L,D]
    const int b = bh >> 4, h = bh & 15;
#pragma unroll
    for (int qf = 0; qf < 2; qf++) {
        float l = l_part[qf];
        l += __shfl_xor(l, 16, 64);
        l += __shfl_xor(l, 32, 64);
        const float inv = 1.f / l;
        const int q = qw + qf * 16 + (lane & 15);
#pragma unroll
        for (int dkf = 0; dkf < 4; dkf++) {
            const int dk0 = dkf * 16 + (lane >> 4) * 4;
            u32x2 o;
            o[0] = pk2(accT[dkf][qf][0] * inv, accT[dkf][qf][1] * inv);
            o[1] = pk2(accT[dkf][qf][2] * inv, accT[dkf][qf][3] * inv);
            long addr = ((long)b * Lseq + q) * Dm + h * Dk + dk0;
            *(u32x2*)(Ctx + addr) = o;
        }
    }
}

// ---------------------------------------------------------------------------
extern "C" void kernel_launch(void* const* d_in, const int* in_sizes, int n_in,
                              void* d_out, int out_size, void* d_ws, size_t ws_size,
                              hipStream_t stream)
{
    const float* query = (const float*)d_in[0];
    const float* key_  = (const float*)d_in[1];
    const float* value = (const float*)d_in[2];
    const float* Wq = (const float*)d_in[3];
    const float* bq = (const float*)d_in[4];
    const float* Wk = (const float*)d_in[5];
    const float* bk = (const float*)d_in[6];
    const float* Wv = (const float*)d_in[7];
    const float* bv = (const float*)d_in[8];
    const float* Wo = (const float*)d_in[9];
    const float* bo = (const float*)d_in[10];
    // d_in[11] = attn_mask (bool causal) — derived from indices instead.

    float* out = (float*)d_out;
    const size_t tens = (size_t)Bsz * Lseq * Dm;   // 8,388,608
    const size_t wTot = (size_t)Dm * Dm;           // 1,048,576
    // ws layout (4*tens*2B = 67.1 MB, proven available):
    u16* Qb = (u16*)d_ws;        // bf16 [B,H,L,DK] (Q pre-scaled)
    u16* Kb = Qb + tens;
    u16* Vb = Kb + tens;
    u16* Cx = Vb + tens;         // attn output [B,L,D]
    // weight bf16 buffers alias dead regions:
    u16* Wqb = Cx;               // Wq/Wk/Wv (contiguous) live in Cx slot until attn
    u16* Wkb = Wqb + wTot;
    u16* Wvb = Wkb + wTot;
    u16* Wob = Qb;               // converted AFTER attn (Qb dead by then)

    dim3 blk(256), g(64, 8), gq(64, 24);
    const int n8w = (int)(wTot / 8);
    const int gw = (n8w + 255) / 256;

    cvt_f2b<<<gw, blk, 0, stream>>>(Wq, Wqb, n8w);
    cvt_f2b<<<gw, blk, 0, stream>>>(Wk, Wkb, n8w);
    cvt_f2b<<<gw, blk, 0, stream>>>(Wv, Wvb, n8w);
    gemm_qkv<<<gq, blk, 0, stream>>>(query, key_, value, Wqb, bq, bk, bv, Qb);
    attn_fwd<<<dim3(Bsz * Hn, Lseq / 128), blk, 0, stream>>>(Qb, Kb, Vb, Cx);
    cvt_f2b<<<gw, blk, 0, stream>>>(Wo, Wob, n8w);
    gemm_glds<<<g, blk, 0, stream>>>(Cx, Wob, bo, out, 1.0f);
}

// Round 12
// 215.724 us; speedup vs baseline: 1.1593x; 1.0031x over previous
//
#include <hip/hip_runtime.h>
#include <hip/hip_bf16.h>
#include <stdint.h>

typedef unsigned short u16;
typedef unsigned int u32;
typedef short short8 __attribute__((ext_vector_type(8)));
typedef float f32x4 __attribute__((ext_vector_type(4)));
typedef u32 u32x4 __attribute__((ext_vector_type(4)));
typedef u32 u32x2 __attribute__((ext_vector_type(2)));

#define DEV static __device__ __forceinline__

constexpr int Bsz = 4, Lseq = 2048, Dm = 1024, Hn = 16, Dk = 64;
constexpr float LOG2E = 1.44269504088896340736f;
constexpr float QSCALE = 0.125f * LOG2E;  // folded into Q projection

DEV u16 f2bf(float x) {
    u32 u = __builtin_bit_cast(u32, x);
    return (u16)((u + 0x7fffu + ((u >> 16) & 1u)) >> 16);
}

// pack 2 fp32 -> 2 bf16 in a u32 via HW v_cvt_pk_bf16_f32 path
DEV u32 pk2(float a, float b) {
    __hip_bfloat162 h = __float22bfloat162_rn(float2{a, b});
    u32 r;
    __builtin_memcpy(&r, &h, 4);
    return r;
}

// load 8 consecutive fp32, RNE to bf16, pack as u32x4
DEV u32x4 ld8_cvt(const float* p) {
    f32x4 lo = *(const f32x4*)p;
    f32x4 hi = *(const f32x4*)(p + 4);
    u32x4 r;
    r[0] = pk2(lo[0], lo[1]);
    r[1] = pk2(lo[2], lo[3]);
    r[2] = pk2(hi[0], hi[1]);
    r[3] = pk2(hi[2], hi[3]);
    return r;
}

// async global->LDS, 16B per lane; lds dest = wave-uniform base + lane*16
DEV void glds16(const void* g, void* l) {
    __builtin_amdgcn_global_load_lds(
        (const __attribute__((address_space(1))) void*)g,
        (__attribute__((address_space(3))) void*)l, 16, 0, 0);
}

// ---------------------------------------------------------------------------
// fp32 -> bf16 conversion: 3 weight matrices in one dispatch.
// blockIdx.y selects source; dest = d + y*n8*8 (contiguous slabs).
// ---------------------------------------------------------------------------
__global__ __launch_bounds__(256) void cvt_w3(
    const float* __restrict__ a, const float* __restrict__ b,
    const float* __restrict__ c, u16* __restrict__ d, int n8)
{
    int i = blockIdx.x * 256 + threadIdx.x;
    if (i >= n8) return;
    const float* s = blockIdx.y == 0 ? a : (blockIdx.y == 1 ? b : c);
    ((u32x4*)(d + (size_t)blockIdx.y * (size_t)n8 * 8))[i] = ld8_cvt(s + (long)i * 8);
}

// ---------------------------------------------------------------------------
// Output projection: out[M,N] fp32 = Cx[M,1024](bf16) @ Wo[N,1024]^T + bo.
// A-side: bf16 via global_load_lds w=16 (gemm_glds-proven).
// B-side: fp32 reg-staged with in-flight cvt (gemm_bt/R4-proven B-path).
// 128x128 tile, BK=32, 4 waves (2x2). Removes the separate Wo cvt pass.
// ---------------------------------------------------------------------------
__global__ __launch_bounds__(256) void gemm_oproj(
    const u16* __restrict__ A, const float* __restrict__ W,
    const float* __restrict__ bias, float* __restrict__ Cout)
{
    __shared__ u16 At[2][128 * 32];
    __shared__ u16 Bt[2][128 * 32];

    const int tid = threadIdx.x;
    const int lane = tid & 63, wid = tid >> 6;
    const int wr = wid >> 1, wc = wid & 1;
    const int mbase = blockIdx.x * 128, nbase = blockIdx.y * 128;

    f32x4 acc[4][4];
#pragma unroll
    for (int i = 0; i < 4; i++)
#pragma unroll
        for (int j = 0; j < 4; j++) acc[i][j] = (f32x4)0.f;

    // A staging via glds (proven)
    const int srow = lane >> 2;
    const int sseg = (lane & 3) * 8;
    auto stageA = [&](int kt, int buf) {
#pragma unroll
        for (int c = 0; c < 2; c++) {
            const int sec = wid * 2 + c;
            glds16(A + (long)(mbase + sec * 16 + srow) * Dm + (long)kt * 32 + sseg,
                   &At[buf][sec * 512]);
        }
    };

    // B staging: fp32 W reg-staged + in-flight cvt (proven R4 pattern)
    u32x4 vb[2];
    auto loadB = [&](int kt) {
#pragma unroll
        for (int i = 0; i < 2; i++) {
            int idx = i * 256 + tid;
            int row = idx >> 2, seg = idx & 3;
            vb[i] = ld8_cvt(W + (long)(nbase + row) * Dm + (long)kt * 32 + seg * 8);
        }
    };
    auto writeB = [&](int buf) {
#pragma unroll
        for (int i = 0; i < 2; i++) {
            int idx = i * 256 + tid;
            *(u32x4*)&Bt[buf][idx * 8] = vb[i];
        }
    };

    stageA(0, 0);
    loadB(0);
    writeB(0);
    __syncthreads();

    for (int kt = 0; kt < 32; kt++) {
        const int cur = kt & 1;
        const bool more = (kt + 1 < 32);
        if (more) {
            stageA(kt + 1, cur ^ 1);
            loadB(kt + 1);
        }
        short8 af[4], bfr[4];
#pragma unroll
        for (int mf = 0; mf < 4; mf++)
            af[mf] = *(const short8*)&At[cur][(wr * 64 + mf * 16 + (lane & 15)) * 32 + (lane >> 4) * 8];
#pragma unroll
        for (int nf = 0; nf < 4; nf++)
            bfr[nf] = *(const short8*)&Bt[cur][(wc * 64 + nf * 16 + (lane & 15)) * 32 + (lane >> 4) * 8];
        __builtin_amdgcn_s_setprio(1);
#pragma unroll
        for (int mf = 0; mf < 4; mf++)
#pragma unroll
            for (int nf = 0; nf < 4; nf++)
                acc[mf][nf] = __builtin_amdgcn_mfma_f32_16x16x32_bf16(af[mf], bfr[nf], acc[mf][nf], 0, 0, 0);
        __builtin_amdgcn_s_setprio(0);
        if (more) writeB(cur ^ 1);
        __syncthreads();
    }

#pragma unroll
    for (int nf = 0; nf < 4; nf++) {
        const int n = nbase + wc * 64 + nf * 16 + (lane & 15);
        const float bv = bias[n];
#pragma unroll
        for (int mf = 0; mf < 4; mf++) {
            const int m0 = mbase + wr * 64 + mf * 16 + (lane >> 4) * 4;
#pragma unroll
            for (int r = 0; r < 4; r++) {
                const int m = m0 + r;
                Cout[(long)m * Dm + n] = acc[mf][nf][r] + bv;
            }
        }
    }
}

// ---------------------------------------------------------------------------
// Fused QKV GEMM (R9/R11-proven): one 1536-block dispatch computes all three
// projections. t = blockIdx.y>>3 selects {X, W slab, bias, scale, output}.
// A fp32 reg-staged with in-flight cvt; B bf16 via glds w=16.
// Out: bf16 headed [B,H,L,DK].
// ---------------------------------------------------------------------------
__global__ __launch_bounds__(256) void gemm_qkv(
    const float* __restrict__ Xq, const float* __restrict__ Xk,
    const float* __restrict__ Xv, const u16* __restrict__ Wb3,
    const float* __restrict__ bq, const float* __restrict__ bk,
    const float* __restrict__ bv, u16* __restrict__ Out3)
{
    __shared__ u16 At[2][128 * 32];
    __shared__ u16 Bt[2][128 * 32];

    const int tid = threadIdx.x;
    const int lane = tid & 63, wid = tid >> 6;
    const int wr = wid >> 1, wc = wid & 1;
    const int mbase = blockIdx.x * 128;
    const int t = blockIdx.y >> 3;              // 0:Q 1:K 2:V (block-uniform)
    const int nbase = (blockIdx.y & 7) * 128;
    const float* X = t == 0 ? Xq : (t == 1 ? Xk : Xv);
    const u16* Bw = Wb3 + (size_t)t * Dm * Dm;
    const float* bias = t == 0 ? bq : (t == 1 ? bk : bv);
    const float scale = t == 0 ? QSCALE : 1.0f;
    u16* Cout = Out3 + (size_t)t * ((size_t)Bsz * Lseq * Dm);

    f32x4 acc[4][4];
#pragma unroll
    for (int i = 0; i < 4; i++)
#pragma unroll
        for (int j = 0; j < 4; j++) acc[i][j] = (f32x4)0.f;

    // B staging (glds, proven)
    const int srow = lane >> 2;
    const int sseg = (lane & 3) * 8;
    auto stageB = [&](int kt, int buf) {
#pragma unroll
        for (int c = 0; c < 2; c++) {
            const int sec = wid * 2 + c;
            glds16(Bw + (long)(nbase + sec * 16 + srow) * Dm + (long)kt * 32 + sseg,
                   &Bt[buf][sec * 512]);
        }
    };

    // A staging (reg + in-flight cvt, proven)
    u32x4 va[2];
    auto loadA = [&](int kt) {
#pragma unroll
        for (int i = 0; i < 2; i++) {
            int idx = i * 256 + tid;
            int row = idx >> 2, seg = idx & 3;
            va[i] = ld8_cvt(X + (long)(mbase + row) * Dm + (long)kt * 32 + seg * 8);
        }
    };
    auto writeA = [&](int buf) {
#pragma unroll
        for (int i = 0; i < 2; i++) {
            int idx = i * 256 + tid;
            *(u32x4*)&At[buf][idx * 8] = va[i];
        }
    };

    stageB(0, 0);
    loadA(0);
    writeA(0);
    __syncthreads();

    for (int kt = 0; kt < 32; kt++) {
        const int cur = kt & 1;
        const bool more = (kt + 1 < 32);
        if (more) {
            stageB(kt + 1, cur ^ 1);
            loadA(kt + 1);
        }
        short8 af[4], bfr[4];
#pragma unroll
        for (int mf = 0; mf < 4; mf++)
            af[mf] = *(const short8*)&At[cur][(wr * 64 + mf * 16 + (lane & 15)) * 32 + (lane >> 4) * 8];
#pragma unroll
        for (int nf = 0; nf < 4; nf++)
            bfr[nf] = *(const short8*)&Bt[cur][(wc * 64 + nf * 16 + (lane & 15)) * 32 + (lane >> 4) * 8];
        __builtin_amdgcn_s_setprio(1);
#pragma unroll
        for (int mf = 0; mf < 4; mf++)
#pragma unroll
            for (int nf = 0; nf < 4; nf++)
                acc[mf][nf] = __builtin_amdgcn_mfma_f32_16x16x32_bf16(af[mf], bfr[nf], acc[mf][nf], 0, 0, 0);
        __builtin_amdgcn_s_setprio(0);
        if (more) writeA(cur ^ 1);
        __syncthreads();
    }

#pragma unroll
    for (int nf = 0; nf < 4; nf++) {
        const int n = nbase + wc * 64 + nf * 16 + (lane & 15);
        const float bv = bias[n];
#pragma unroll
        for (int mf = 0; mf < 4; mf++) {
            const int m0 = mbase + wr * 64 + mf * 16 + (lane >> 4) * 4;
#pragma unroll
            for (int r = 0; r < 4; r++) {
                const int m = m0 + r;
                const float v = (acc[mf][nf][r] + bv) * scale;
                int b = m >> 11, l = m & 2047, h = n >> 6, dk = n & 63;
                long addr = ((long)(b * Hn + h) * Lseq + l) * Dk + dk;
                Cout[addr] = f2bf(v);
            }
        }
    }
}

// ---------------------------------------------------------------------------
// Flash attention (R7/R11-proven, 48KB full-P). Causal, base-2 softmax
// (Q pre-scaled by 1/8*log2e). Grid: (B*H, L/128), qt reversed. 4 waves,
// wave w owns q rows [qt*128+w*32, +32). Double-buffered K/V, 1 barrier/iter.
// K: glds w=16 with pre-swizzled source; read col ^ ((kv&7)<<3).
// V: reg transpose-staged Vt[d][kv ^ (((d&7)^(d>>3))<<3)].
// P per-wave [32q][64kv], col ^ ((q&7)<<3). Defer-max (THR=8) +
// lane-partial l. setprio around MFMA clusters.
// ---------------------------------------------------------------------------
__global__ __launch_bounds__(256) void attn_fwd(
    const u16* __restrict__ Qb, const u16* __restrict__ Kb,
    const u16* __restrict__ Vb, u16* __restrict__ Ctx)
{
    __shared__ u16 Kt[2][64 * 64];
    __shared__ u16 Vt[2][64 * 64];
    __shared__ u16 Pq[4][32 * 64];

    const int tid = threadIdx.x, lane = tid & 63, w = tid >> 6;
    const int qt = gridDim.y - 1 - blockIdx.y;  // heavy-first
    const int bh = blockIdx.x;
    const long base = (long)bh * Lseq * Dk;
    const int qw = qt * 128 + w * 32;

    const int krow_in_w = lane >> 3;
    const int kseg = lane & 7;
    const int skv = tid >> 3, sdb = (tid & 7) * 8;

    auto stage_k = [&](int kvbase, int buf) {
#pragma unroll
        for (int c = 0; c < 2; c++) {
            int kv = w * 16 + c * 8 + krow_in_w;
            int d0 = ((kseg ^ (kv & 7)) * 8);
            glds16(Kb + base + (long)(kvbase + kv) * Dk + d0,
                   &Kt[buf][(w * 16 + c * 8) * 64]);
        }
    };

    // Q fragments in registers (log2 domain)
    short8 qfr[2][2];
#pragma unroll
    for (int qf = 0; qf < 2; qf++)
#pragma unroll
        for (int ks = 0; ks < 2; ks++) {
            int q = qw + qf * 16 + (lane & 15);
            int d0 = ks * 32 + (lane >> 4) * 8;
            qfr[qf][ks] = *(const short8*)(Qb + base + (long)q * Dk + d0);
        }

    f32x4 accT[4][2];  // ctx^T: [dkf][qf]
#pragma unroll
    for (int i = 0; i < 4; i++)
#pragma unroll
        for (int j = 0; j < 2; j++) accT[i][j] = (f32x4)0.f;
    float m_run[2] = {-__builtin_inff(), -__builtin_inff()};
    float l_part[2] = {0.f, 0.f};

    u32x4 vr[2];
    stage_k(0, 0);
#pragma unroll
    for (int i = 0; i < 2; i++)
        vr[i] = *(const u32x4*)(Vb + base + (long)(i * 32 + skv) * Dk + sdb);
#pragma unroll
    for (int i = 0; i < 2; i++) {
        int kv = i * 32 + skv;
        const u16* pv = (const u16*)&vr[i];
#pragma unroll
        for (int j = 0; j < 8; j++) {
            int d = sdb + j;
            Vt[0][d * 64 + (kv ^ ((((d & 7) ^ (d >> 3)) & 7) << 3))] = pv[j];
        }
    }
    __syncthreads();

    const int nkv = qt * 2 + 2;
    const int myn = ((qw + 31) >> 6) + 1;  // tiles this wave computes

    for (int kvt = 0; kvt < nkv; kvt++) {
        const int cur = kvt & 1;
        const bool more = (kvt + 1 < nkv);
        const int kvbase = kvt * 64;

        if (more) {
            stage_k(kvbase + 64, cur ^ 1);
#pragma unroll
            for (int i = 0; i < 2; i++)
                vr[i] = *(const u32x4*)(Vb + base + (long)(kvbase + 64 + i * 32 + skv) * Dk + sdb);
        }

        if (kvt < myn) {
            // ---- S^T = K @ Q^T
            f32x4 st[4][2];
#pragma unroll
            for (int i = 0; i < 4; i++)
#pragma unroll
                for (int j = 0; j < 2; j++) st[i][j] = (f32x4)0.f;
            __builtin_amdgcn_s_setprio(1);
#pragma unroll
            for (int ks = 0; ks < 2; ks++) {
                short8 kf[4];
#pragma unroll
                for (int kvf = 0; kvf < 4; kvf++) {
                    int row = kvf * 16 + (lane & 15);
                    int d0 = ks * 32 + (lane >> 4) * 8;
                    kf[kvf] = *(const short8*)&Kt[cur][row * 64 + (d0 ^ ((row & 7) << 3))];
                }
#pragma unroll
                for (int kvf = 0; kvf < 4; kvf++)
#pragma unroll
                    for (int qf = 0; qf < 2; qf++)
                        st[kvf][qf] = __builtin_amdgcn_mfma_f32_16x16x32_bf16(kf[kvf], qfr[qf][ks], st[kvf][qf], 0, 0, 0);
            }
            __builtin_amdgcn_s_setprio(0);

            // ---- causal mask (diagonal tiles only)
            if ((kvbase + 63) > qw) {
#pragma unroll
                for (int qf = 0; qf < 2; qf++) {
                    const int q = qw + qf * 16 + (lane & 15);
#pragma unroll
                    for (int kvf = 0; kvf < 4; kvf++)
#pragma unroll
                        for (int r = 0; r < 4; r++) {
                            int kv = kvbase + kvf * 16 + (lane >> 4) * 4 + r;
                            if (kv > q) st[kvf][qf][r] = -1e30f;
                        }
                }
            }

            // ---- online softmax (base 2), defer-max, lane-partial l
#pragma unroll
            for (int qf = 0; qf < 2; qf++) {
                float tmax = st[0][qf][0];
#pragma unroll
                for (int kvf = 0; kvf < 4; kvf++)
#pragma unroll
                    for (int r = 0; r < 4; r++) tmax = fmaxf(tmax, st[kvf][qf][r]);
                tmax = fmaxf(tmax, __shfl_xor(tmax, 16, 64));
                tmax = fmaxf(tmax, __shfl_xor(tmax, 32, 64));
                const bool norescale = __all((int)(tmax <= m_run[qf] + 8.f));
                if (!norescale) {
                    const float mnew = fmaxf(m_run[qf], tmax);
                    const float sc = __builtin_exp2f(m_run[qf] - mnew);
                    m_run[qf] = mnew;
                    l_part[qf] *= sc;
#pragma unroll
                    for (int dkf = 0; dkf < 4; dkf++)
#pragma unroll
                        for (int r = 0; r < 4; r++) accT[dkf][qf][r] *= sc;
                }
                const float mq = m_run[qf];
                float ts = 0.f;
#pragma unroll
                for (int kvf = 0; kvf < 4; kvf++)
#pragma unroll
                    for (int r = 0; r < 4; r++) {
                        float p = __builtin_exp2f(st[kvf][qf][r] - mq);
                        st[kvf][qf][r] = p;
                        ts += p;
                    }
                l_part[qf] += ts;
                const int qrow = qf * 16 + (lane & 15);
#pragma unroll
                for (int kvf = 0; kvf < 4; kvf++) {
                    u32x2 pk;
                    pk[0] = pk2(st[kvf][qf][0], st[kvf][qf][1]);
                    pk[1] = pk2(st[kvf][qf][2], st[kvf][qf][3]);
                    int kvi = (kvf * 16 + (lane >> 4) * 4) ^ ((lane & 7) << 3);
                    *(u32x2*)&Pq[w][qrow * 64 + kvi] = pk;
                }
            }

            // ---- PV: ctx^T += V^T @ P^T
#pragma unroll
            for (int kf2 = 0; kf2 < 2; kf2++) {
                short8 vfr[4];
#pragma unroll
                for (int dkf = 0; dkf < 4; dkf++) {
                    int d = dkf * 16 + (lane & 15);
                    int kvi = (kf2 * 32 + (lane >> 4) * 8) ^ ((((d & 7) ^ (d >> 3)) & 7) << 3);
                    vfr[dkf] = *(const short8*)&Vt[cur][d * 64 + kvi];
                }
                short8 pfr[2];
#pragma unroll
                for (int qf = 0; qf < 2; qf++) {
                    int qrow = qf * 16 + (lane & 15);
                    int kvi = (kf2 * 32 + (lane >> 4) * 8) ^ ((lane & 7) << 3);
                    pfr[qf] = *(const short8*)&Pq[w][qrow * 64 + kvi];
                }
                __builtin_amdgcn_s_setprio(1);
#pragma unroll
                for (int dkf = 0; dkf < 4; dkf++)
#pragma unroll
                    for (int qf = 0; qf < 2; qf++)
                        accT[dkf][qf] = __builtin_amdgcn_mfma_f32_16x16x32_bf16(vfr[dkf], pfr[qf], accT[dkf][qf], 0, 0, 0);
                __builtin_amdgcn_s_setprio(0);
            }
        }

        // write staged V regs into the other buffer
        if (more) {
#pragma unroll
            for (int i = 0; i < 2; i++) {
                int kv = i * 32 + skv;
                const u16* pv = (const u16*)&vr[i];
#pragma unroll
                for (int j = 0; j < 8; j++) {
                    int d = sdb + j;
                    Vt[cur ^ 1][d * 64 + (kv ^ ((((d & 7) ^ (d >> 3)) & 7) << 3))] = pv[j];
                }
            }
        }
        __syncthreads();  // drains glds (vmcnt) for buf^1
    }

    // ---- epilogue: reduce l, divide, write bf16 [B,L,D]
    const int b = bh >> 4, h = bh & 15;
#pragma unroll
    for (int qf = 0; qf < 2; qf++) {
        float l = l_part[qf];
        l += __shfl_xor(l, 16, 64);
        l += __shfl_xor(l, 32, 64);
        const float inv = 1.f / l;
        const int q = qw + qf * 16 + (lane & 15);
#pragma unroll
        for (int dkf = 0; dkf < 4; dkf++) {
            const int dk0 = dkf * 16 + (lane >> 4) * 4;
            u32x2 o;
            o[0] = pk2(accT[dkf][qf][0] * inv, accT[dkf][qf][1] * inv);
            o[1] = pk2(accT[dkf][qf][2] * inv, accT[dkf][qf][3] * inv);
            long addr = ((long)b * Lseq + q) * Dm + h * Dk + dk0;
            *(u32x2*)(Ctx + addr) = o;
        }
    }
}

// ---------------------------------------------------------------------------
extern "C" void kernel_launch(void* const* d_in, const int* in_sizes, int n_in,
                              void* d_out, int out_size, void* d_ws, size_t ws_size,
                              hipStream_t stream)
{
    const float* query = (const float*)d_in[0];
    const float* key_  = (const float*)d_in[1];
    const float* value = (const float*)d_in[2];
    const float* Wq = (const float*)d_in[3];
    const float* bq = (const float*)d_in[4];
    const float* Wk = (const float*)d_in[5];
    const float* bk = (const float*)d_in[6];
    const float* Wv = (const float*)d_in[7];
    const float* bv = (const float*)d_in[8];
    const float* Wo = (const float*)d_in[9];
    const float* bo = (const float*)d_in[10];
    // d_in[11] = attn_mask (bool causal) — derived from indices instead.

    float* out = (float*)d_out;
    const size_t tens = (size_t)Bsz * Lseq * Dm;   // 8,388,608
    const size_t wTot = (size_t)Dm * Dm;           // 1,048,576
    // ws layout (4*tens*2B = 67.1 MB, proven available):
    u16* Qb = (u16*)d_ws;        // bf16 [B,H,L,DK] (Q pre-scaled)
    u16* Kb = Qb + tens;
    u16* Vb = Kb + tens;
    u16* Cx = Vb + tens;         // attn output [B,L,D]
    u16* Wqb = Cx;               // Wq/Wk/Wv bf16 live in Cx slot until attn

    dim3 blk(256), g(64, 8), gq(64, 24);
    const int n8w = (int)(wTot / 8);
    const int gw = (n8w + 255) / 256;

    cvt_w3<<<dim3(gw, 3), blk, 0, stream>>>(Wq, Wk, Wv, Wqb, n8w);
    gemm_qkv<<<gq, blk, 0, stream>>>(query, key_, value, Wqb, bq, bk, bv, Qb);
    attn_fwd<<<dim3(Bsz * Hn, Lseq / 128), blk, 0, stream>>>(Qb, Kb, Vb, Cx);
    gemm_oproj<<<g, blk, 0, stream>>>(Cx, Wo, bo, out);
}